// Round 16
// baseline (213.739 us; speedup 1.0000x reference)
//
#include <hip/hip_runtime.h>
#include <hip/hip_fp16.h>
#include <math.h>

#define N_ 100000
#define E_ 3200000
#define K_ 1024
#define D_ 11
#define NBUCK_ 391            // ceil(N/256) buckets of 256 nodes (by src>>8)
#define NPAD_ (NBUCK_ * 256)  // 100096 padded node count
#define CAPB_ 16384           // global slots per bucket (mean fill ~8184)
#define CAP_ 16               // LDS staging slots per bucket (one 64B line)
#define CAPW_ 17              // padded stride: bank = (17b+pos)%32, odd -> uniform
#define GB_ 1024              // binning blocks (4/CU: occupancy was k_bin's limiter)
#define CHUNK_ 3128           // edges per binning block (mult of 8; 1024*3128 >= E)
#define SA_ 8                 // segments per bucket for k_agg (seg <= 2048)
#define SD_ 8                 // segments per bucket for k_deg
#define SP_ 4                 // segments per bucket for k_pr
#define XC_ 32                // xmean partial copies (spread atomic contention)

static inline size_t align512(size_t x) { return (x + 511) & ~(size_t)511; }

__device__ inline float2 h2f(unsigned int u) {
    __half2 h = *reinterpret_cast<__half2*>(&u);
    return __half22float2(h);
}

// ------- prep: zero state, seed cursors, pad x->fp16, flag via binsearch ----
__global__ void k_prep(const float* __restrict__ x, const int* __restrict__ ready,
                       __half* __restrict__ xh,
                       int* __restrict__ deg, float* __restrict__ pr_raw,
                       unsigned char* __restrict__ flag, float* __restrict__ xpart,
                       int* __restrict__ bcur) {
    int i = blockIdx.x * blockDim.x + threadIdx.x;
    if (i < N_ * 16) {
        int n = i >> 4, j = i & 15;
        if (j < D_) xh[i] = __float2half_rn(x[n * D_ + j]);
        // j==11: dis (k_dis); 12..15: never read
    }
    if (i < N_) {
        deg[i] = 0; pr_raw[i] = 0.f;
        // membership of i in sorted ready[] (binary search, dups ok)
        int lo = 0, hi = K_ - 1, f = 0;
        while (lo <= hi) {
            int mid = (lo + hi) >> 1;
            int v = ready[mid];
            if (v == i) { f = 1; break; }
            if (v < i) lo = mid + 1; else hi = mid - 1;
        }
        flag[i] = (unsigned char)f;
    }
    if (i < XC_ * 64) xpart[i] = 0.f;
    if (i < NBUCK_) bcur[i] = i * CAPB_;
}

// ---- bucket partition v4: small CAP (28KB LDS -> 4 blocks/CU), single drain
// pack = (src&255)<<17 | dst
__global__ __launch_bounds__(256) void k_bin(const int* __restrict__ src,
                                             const int* __restrict__ dst,
                                             int* __restrict__ bcur,
                                             int* __restrict__ gbuf) {
    __shared__ int sbuf[NBUCK_ * CAPW_];   // ~26.6 KB, stride 17
    __shared__ int scnt[NBUCK_];
    int t = threadIdx.x;
    for (int b = t; b < NBUCK_; b += 256) scnt[b] = 0;
    __syncthreads();
    long e0 = (long)blockIdx.x * CHUNK_;
    // stage whole chunk, no internal barriers: per-bucket load ~Poisson(8),
    // CAP=16 overflows w.p. ~0.4% -> scattered fallback (~3k edges total)
    for (int r = 0; r < CHUNK_; r += 2048) {
        int off = r + t * 8;
        long i0 = e0 + off;
        if (off < CHUNK_ && i0 + 7 < E_) {   // CHUNK_%8==0: all-or-nothing
            int4 s0 = *(const int4*)(src + i0);
            int4 s1 = *(const int4*)(src + i0 + 4);
            int4 d0 = *(const int4*)(dst + i0);
            int4 d1 = *(const int4*)(dst + i0 + 4);
            int ss[8] = {s0.x, s0.y, s0.z, s0.w, s1.x, s1.y, s1.z, s1.w};
            int dd[8] = {d0.x, d0.y, d0.z, d0.w, d1.x, d1.y, d1.z, d1.w};
#pragma unroll
            for (int q = 0; q < 8; q++) {
                int b = ss[q] >> 8;
                int pack = ((ss[q] & 255) << 17) | dd[q];
                int pos = atomicAdd(&scnt[b], 1);
                if (pos < CAP_) sbuf[b * CAPW_ + pos] = pack;
                else gbuf[atomicAdd(&bcur[b], 1)] = pack;  // rare fallback
            }
        }
    }
    __syncthreads();
    // single drain: at most one 64B-line flush + contiguous partial per bucket
    for (int b = t; b < NBUCK_; b += 256) {
        int c = min(scnt[b], CAP_);
        while (c >= 16) {
            int g = atomicAdd(&bcur[b], 16);
            c -= 16;
            if ((g & 3) == 0) {
                int4* gp = (int4*)(gbuf + g);
#pragma unroll
                for (int q = 0; q < 4; q++)
                    gp[q] = make_int4(sbuf[b*CAPW_ + c + 4*q],
                                      sbuf[b*CAPW_ + c + 4*q + 1],
                                      sbuf[b*CAPW_ + c + 4*q + 2],
                                      sbuf[b*CAPW_ + c + 4*q + 3]);
            } else {
                for (int k = 0; k < 16; k++) gbuf[g + k] = sbuf[b*CAPW_ + c + k];
            }
        }
        if (c > 0) {
            int g = atomicAdd(&bcur[b], c);
            for (int k = 0; k < c; k++) gbuf[g + k] = sbuf[b*CAPW_ + k];
        }
    }
}

// ---------------- per-bucket-segment degree hist (int4 loads) ---------------
__global__ __launch_bounds__(256) void k_deg(const int* __restrict__ bcur,
                                             const int* __restrict__ gbuf,
                                             int* __restrict__ deg) {
    __shared__ int hist[256];
    int t = threadIdx.x, b = blockIdx.x, s = blockIdx.y;
    hist[t] = 0;
    __syncthreads();
    int base = b * CAPB_;
    int cnt = min(bcur[b] - base, CAPB_);
    int seg = (((cnt + SD_ - 1) / SD_) + 3) & ~3;   // mult of 4: int4-aligned lo
    int lo = s * seg, hi = min(lo + seg, cnt);
    int p = lo + t * 4;
    for (; p + 3 < hi; p += 1024) {
        int4 v = *(const int4*)(gbuf + base + p);
        atomicAdd(&hist[v.x >> 17], 1);
        atomicAdd(&hist[v.y >> 17], 1);
        atomicAdd(&hist[v.z >> 17], 1);
        atomicAdd(&hist[v.w >> 17], 1);
    }
    if (p < hi) {   // tail group (<4)
        for (int q = p; q < hi; q++) atomicAdd(&hist[gbuf[base + q] >> 17], 1);
    }
    __syncthreads();
    int node = (b << 8) + t;
    if (node < N_ && hist[t]) atomicAdd(&deg[node], hist[t]);
}

// ---------------- dis = rsqrt(deg+1); pack fp16 copy into xh slot 11 --------
__global__ void k_dis(const int* __restrict__ deg, float* __restrict__ dis,
                      __half* __restrict__ xh) {
    int i = blockIdx.x * blockDim.x + threadIdx.x;
    if (i >= N_) return;
    float dv = rsqrtf((float)(deg[i] + 1));
    dis[i] = dv;
    xh[(size_t)i * 16 + 11] = __float2half_rn(dv);
}

// ------- k_agg: LDS counting-sort by node, register accumulate --------------
__global__ __launch_bounds__(256) void k_agg(const int* __restrict__ bcur,
                                             const int* __restrict__ gbuf,
                                             const __half* __restrict__ xh,
                                             float* __restrict__ upart) {
    __shared__ int sorted[2048];   // seg <= ceil(16384/8) = 2048
    __shared__ int hist[256];
    __shared__ int incl[256];
    __shared__ int offa[256];
    int t = threadIdx.x, b = blockIdx.x, s = blockIdx.y;
    hist[t] = 0;
    __syncthreads();
    int base = b * CAPB_;
    int cnt = min(bcur[b] - base, CAPB_);
    int seg = (cnt + SA_ - 1) / SA_;
    int lo = s * seg, hi = min(lo + seg, cnt);
    int segn = hi - lo;                       // <= 2048
    int kmax = (segn + 255) >> 8;             // <= 8
    int pk[8], rk[8];
    for (int k = 0; k < kmax; k++) {
        int idx = lo + (k << 8) + t;
        if (idx < hi) {
            pk[k] = gbuf[base + idx];         // coalesced
            rk[k] = atomicAdd(&hist[pk[k] >> 17], 1);
        } else pk[k] = -1;
    }
    __syncthreads();
    incl[t] = hist[t];
    __syncthreads();
    for (int off = 1; off < 256; off <<= 1) {
        int v = (t >= off) ? incl[t - off] : 0;
        __syncthreads();
        incl[t] += v;
        __syncthreads();
    }
    offa[t] = incl[t] - hist[t];
    __syncthreads();
    for (int k = 0; k < kmax; k++) {
        if (pk[k] >= 0) sorted[offa[pk[k] >> 17] + rk[k]] = pk[k];
    }
    __syncthreads();
    int my_start = offa[t], my_cnt = hist[t];
    const uint4* xr = (const uint4*)xh;
    float acc[D_];
#pragma unroll
    for (int j = 0; j < D_; j++) acc[j] = 0.f;
    int i = 0;
    for (; i + 3 < my_cnt; i += 4) {          // 4-edge ILP batch
        int pp[4];
#pragma unroll
        for (int q = 0; q < 4; q++) pp[q] = sorted[my_start + i + q];
        uint4 A[4], B[4];
#pragma unroll
        for (int q = 0; q < 4; q++) {
            size_t r = (size_t)(pp[q] & 131071) * 2;
            A[q] = xr[r]; B[q] = xr[r + 1];
        }
#pragma unroll
        for (int q = 0; q < 4; q++) {
            float2 f0 = h2f(A[q].x), f1 = h2f(A[q].y), f2 = h2f(A[q].z);
            float2 f3 = h2f(A[q].w), f4 = h2f(B[q].x), f5 = h2f(B[q].y);
            float w = f5.y;   // dis[d]
            acc[0]  = fmaf(w, f0.x, acc[0]);
            acc[1]  = fmaf(w, f0.y, acc[1]);
            acc[2]  = fmaf(w, f1.x, acc[2]);
            acc[3]  = fmaf(w, f1.y, acc[3]);
            acc[4]  = fmaf(w, f2.x, acc[4]);
            acc[5]  = fmaf(w, f2.y, acc[5]);
            acc[6]  = fmaf(w, f3.x, acc[6]);
            acc[7]  = fmaf(w, f3.y, acc[7]);
            acc[8]  = fmaf(w, f4.x, acc[8]);
            acc[9]  = fmaf(w, f4.y, acc[9]);
            acc[10] = fmaf(w, f5.x, acc[10]);
        }
    }
    for (; i < my_cnt; i++) {
        int pack = sorted[my_start + i];
        size_t r = (size_t)(pack & 131071) * 2;
        uint4 A = xr[r], B = xr[r + 1];
        float2 f0 = h2f(A.x), f1 = h2f(A.y), f2 = h2f(A.z);
        float2 f3 = h2f(A.w), f4 = h2f(B.x), f5 = h2f(B.y);
        float w = f5.y;
        acc[0]  = fmaf(w, f0.x, acc[0]);
        acc[1]  = fmaf(w, f0.y, acc[1]);
        acc[2]  = fmaf(w, f1.x, acc[2]);
        acc[3]  = fmaf(w, f1.y, acc[3]);
        acc[4]  = fmaf(w, f2.x, acc[4]);
        acc[5]  = fmaf(w, f2.y, acc[5]);
        acc[6]  = fmaf(w, f3.x, acc[6]);
        acc[7]  = fmaf(w, f3.y, acc[7]);
        acc[8]  = fmaf(w, f4.x, acc[8]);
        acc[9]  = fmaf(w, f4.y, acc[9]);
        acc[10] = fmaf(w, f5.x, acc[10]);
    }
    float* dst = upart + ((size_t)s * NPAD_ + (b << 8) + t) * 12;
    ((float4*)dst)[0] = make_float4(acc[0], acc[1], acc[2],  acc[3]);
    ((float4*)dst)[1] = make_float4(acc[4], acc[5], acc[6],  acc[7]);
    ((float4*)dst)[2] = make_float4(acc[8], acc[9], acc[10], 0.f);
}

// ---------------- slice reduction: u12[slot] = sum_s upart[s][slot] ---------
__global__ __launch_bounds__(256) void k_red(const float* __restrict__ upart,
                                             float* __restrict__ u12) {
    int slot = blockIdx.x * blockDim.x + threadIdx.x;
    const int TOT = NPAD_ * 3;
    if (slot >= TOT) return;
    const float4* up = (const float4*)upart;
    float4 a = up[slot];
#pragma unroll
    for (int s = 1; s < SA_; s++) {
        float4 v = up[(size_t)s * TOT + slot];
        a.x += v.x; a.y += v.y; a.z += v.z; a.w += v.w;
    }
    ((float4*)u12)[slot] = a;
}

// ------- per-node transform: 4 threads/node, register h, shfl reductions ----
__global__ __launch_bounds__(256) void k_node(
    const float* __restrict__ u12, const float* __restrict__ x,
    const float* __restrict__ dis,
    const float* __restrict__ W1, const float* __restrict__ b1,
    const float* __restrict__ W2,
    float* __restrict__ hd, float* __restrict__ xpart) {
    __shared__ float sW1[D_ * 64];
    __shared__ float sb1[64];
    __shared__ float sW2[75];
    __shared__ float smean[64];
    int t = threadIdx.x;
    for (int k = t; k < D_ * 64; k += 256) sW1[k] = W1[k];
    if (t < 64) { sb1[t] = b1[t]; smean[t] = 0.f; }
    if (t < 75) sW2[t] = W2[t];
    __syncthreads();

    int nl = t >> 2, q = t & 3;
    int node = blockIdx.x * 64 + nl;
    bool valid = node < N_;
    float hreg[16];
    float h2v = 0.f;
    float di = 0.f;
    if (valid) {
        const float4* up = (const float4*)(u12 + (size_t)node * 12);
        float4 u0 = up[0], u1 = up[1], u2 = up[2];
        float acc[D_] = {u0.x, u0.y, u0.z, u0.w, u1.x, u1.y, u1.z, u1.w,
                         u2.x, u2.y, u2.z};
        di = dis[node];
        float xr_[D_], g[D_];
#pragma unroll
        for (int j = 0; j < D_; j++) xr_[j] = x[(size_t)node * D_ + j];
#pragma unroll
        for (int j = 0; j < D_; j++) g[j] = di * (acc[j] + di * xr_[j]);

        int fbase = q << 4;
#pragma unroll
        for (int j = 0; j < 16; j++) {
            int f = fbase + j;
            float a = sb1[f];
#pragma unroll
            for (int jj = 0; jj < D_; jj++) a = fmaf(g[jj], sW1[jj * 64 + f], a);
            float hf = fmaxf(a, 0.f);
            hreg[j] = hf;
            h2v = fmaf(hf, sW2[f], h2v);
        }
        if (q == 0) {
#pragma unroll
            for (int jj = 0; jj < D_; jj++) h2v = fmaf(xr_[jj], sW2[64 + jj], h2v);
        }
    } else {
#pragma unroll
        for (int j = 0; j < 16; j++) hreg[j] = 0.f;
    }
    // h2 = sum of 4 quarter-partials (adjacent lanes)
    h2v += __shfl_xor(h2v, 1);
    h2v += __shfl_xor(h2v, 2);
    if (valid && q == 0) hd[node] = di * h2v;  // pre-scaled for conv2

    // smean: reduce each feature across the 16 same-quarter lanes (stride 4)
    int lane = t & 63;
#pragma unroll
    for (int j = 0; j < 16; j++) {
        float v = hreg[j];
        v += __shfl_xor(v, 4);
        v += __shfl_xor(v, 8);
        v += __shfl_xor(v, 16);
        v += __shfl_xor(v, 32);
        if (lane < 4) atomicAdd(&smean[(lane << 4) + j], v);
    }
    __syncthreads();
    // spread copies: block b -> copy b&(XC_-1); ~49 blocks/copy, no hot line
    if (t < 64) atomicAdd(&xpart[((blockIdx.x & (XC_ - 1)) << 6) + t], smean[t]);
}

// ---------------- per-bucket-segment conv2 (int4 loads, flag-gated) ---------
__global__ __launch_bounds__(256) void k_pr(const int* __restrict__ bcur,
                                            const int* __restrict__ gbuf,
                                            const unsigned char* __restrict__ flag,
                                            const float* __restrict__ hd,
                                            float* __restrict__ pr_raw) {
    __shared__ float prl[256];
    __shared__ unsigned char fl[256];
    int t = threadIdx.x, b = blockIdx.x, s = blockIdx.y;
    prl[t] = 0.f;
    int node = (b << 8) + t;
    fl[t] = (node < N_) ? flag[node] : 0;
    __syncthreads();
    int base = b * CAPB_;
    int cnt = min(bcur[b] - base, CAPB_);
    int seg = (((cnt + SP_ - 1) / SP_) + 3) & ~3;
    int lo = s * seg, hi = min(lo + seg, cnt);
    int p = lo + t * 4;
    for (; p + 3 < hi; p += 1024) {
        int4 v = *(const int4*)(gbuf + base + p);
        int s0 = v.x >> 17, s1 = v.y >> 17, s2 = v.z >> 17, s3 = v.w >> 17;
        if (fl[s0]) atomicAdd(&prl[s0], hd[v.x & 131071]);
        if (fl[s1]) atomicAdd(&prl[s1], hd[v.y & 131071]);
        if (fl[s2]) atomicAdd(&prl[s2], hd[v.z & 131071]);
        if (fl[s3]) atomicAdd(&prl[s3], hd[v.w & 131071]);
    }
    if (p < hi) {
        for (int q = p; q < hi; q++) {
            int pack = gbuf[base + q];
            int sl = pack >> 17;
            if (fl[sl]) atomicAdd(&prl[sl], hd[pack & 131071]);
        }
    }
    __syncthreads();
    if (node < N_ && fl[t] && prl[t] != 0.f) atomicAdd(&pr_raw[node], prl[t]);
}

// ---------------- finalize: logits, prob_nothing, v, softmax ----------------
__global__ __launch_bounds__(1024) void k_final(
    const int* __restrict__ ready, const float* __restrict__ dis,
    const float* __restrict__ hd, const float* __restrict__ pr_raw,
    const float* __restrict__ xpart,
    const float* __restrict__ b2,
    const float* __restrict__ Wd, const float* __restrict__ bd,
    const float* __restrict__ Wv, const float* __restrict__ bv,
    float* __restrict__ out) {
    __shared__ float xm[64];
    __shared__ float red[1024];
    __shared__ float s_max, s_sum, s_pn, s_v;
    int t = threadIdx.x;
    if (t < 64) {
        float s = 0.f;
#pragma unroll
        for (int c = 0; c < XC_; c++) s += xpart[(c << 6) + t];
        xm[t] = s * (1.0f / N_);
    }
    __syncthreads();
    if (t == 0) {
        float pn = bd[0], vv = bv[0];
        for (int f = 0; f < 64; f++) { pn += xm[f] * Wd[f]; vv += xm[f] * Wv[f]; }
        s_pn = pn; s_v = vv;
    }
    int r = ready[t];
    float dr = dis[r];
    float l = dr * (pr_raw[r] + hd[r]) + b2[0];   // dr*Σhd[d] + dr²h2[r] + b2
    __syncthreads();
    float pn = s_pn;
    red[t] = (t == 0) ? fmaxf(l, pn) : l;
    __syncthreads();
    for (int sft = 512; sft > 0; sft >>= 1) {
        if (t < sft) red[t] = fmaxf(red[t], red[t + sft]);
        __syncthreads();
    }
    if (t == 0) s_max = red[0];
    __syncthreads();
    float m = s_max;
    float el = expf(l - m);
    red[t] = el + ((t == 0) ? expf(pn - m) : 0.f);
    __syncthreads();
    for (int sft = 512; sft > 0; sft >>= 1) {
        if (t < sft) red[t] += red[t + sft];
        __syncthreads();
    }
    if (t == 0) s_sum = red[0];
    __syncthreads();
    float inv = 1.0f / s_sum;
    out[t] = el * inv;
    if (t == 0) {
        out[K_] = expf(pn - m) * inv;   // prob_nothing slot
        out[K_ + 1] = s_v;              // v
    }
}

extern "C" void kernel_launch(void* const* d_in, const int* in_sizes, int n_in,
                              void* d_out, int out_size, void* d_ws, size_t ws_size,
                              hipStream_t stream) {
    const float* x    = (const float*)d_in[0];
    const int*   ei   = (const int*)d_in[1];
    const int*   src  = ei;
    const int*   dst  = ei + E_;
    const int*   ready= (const int*)d_in[2];
    const float* W1   = (const float*)d_in[3];
    const float* b1   = (const float*)d_in[4];
    const float* W2   = (const float*)d_in[5];
    const float* b2   = (const float*)d_in[6];
    const float* Wd   = (const float*)d_in[7];
    const float* bd   = (const float*)d_in[8];
    const float* Wv   = (const float*)d_in[9];
    const float* bv   = (const float*)d_in[10];
    float* out = (float*)d_out;

    char* ws = (char*)d_ws;
    size_t o = 0;
    int*   bcur   = (int*)(ws + o);          o += align512(NBUCK_ * sizeof(int));
    int*   gbuf   = (int*)(ws + o);          o += align512((size_t)NBUCK_ * CAPB_ * sizeof(int));
    float* upart  = (float*)(ws + o);        o += align512((size_t)SA_ * NPAD_ * 12 * sizeof(float));
    float* u12    = (float*)(ws + o);        o += align512((size_t)NPAD_ * 12 * sizeof(float));
    __half* xh    = (__half*)(ws + o);       o += align512((size_t)N_ * 16 * sizeof(__half));
    int*   deg    = (int*)(ws + o);          o += align512(N_ * sizeof(int));
    float* dis    = (float*)(ws + o);        o += align512(N_ * sizeof(float));
    float* hd     = (float*)(ws + o);        o += align512(N_ * sizeof(float));
    float* pr_raw = (float*)(ws + o);        o += align512(N_ * sizeof(float));
    unsigned char* flag = (unsigned char*)(ws + o); o += align512(N_);
    float* xpart  = (float*)(ws + o);        o += align512(XC_ * 64 * sizeof(float));

    const int B = 256;
    int g_node  = (N_ + B - 1) / B;
    int g_node4 = (N_ + 63) / 64;          // 4 threads per node
    int g_prep  = (N_ * 16 + B - 1) / B;
    int g_red   = (NPAD_ * 3 + B - 1) / B;
    dim3 gdeg(NBUCK_, SD_);
    dim3 gagg(NBUCK_, SA_);
    dim3 gpr(NBUCK_, SP_);

    k_prep <<<g_prep, B, 0, stream>>>(x, ready, xh, deg, pr_raw, flag, xpart, bcur);
    k_bin  <<<GB_, B, 0, stream>>>(src, dst, bcur, gbuf);
    k_deg  <<<gdeg, B, 0, stream>>>(bcur, gbuf, deg);
    k_dis  <<<g_node, B, 0, stream>>>(deg, dis, xh);
    k_agg  <<<gagg, B, 0, stream>>>(bcur, gbuf, xh, upart);
    k_red  <<<g_red, B, 0, stream>>>(upart, u12);
    k_node <<<g_node4, B, 0, stream>>>(u12, x, dis, W1, b1, W2, hd, xpart);
    k_pr   <<<gpr, B, 0, stream>>>(bcur, gbuf, flag, hd, pr_raw);
    k_final<<<1, 1024, 0, stream>>>(ready, dis, hd, pr_raw, xpart,
                                    b2, Wd, bd, Wv, bv, out);
}

// Round 17
// 211.095 us; speedup vs baseline: 1.0125x; 1.0125x over previous
//
#include <hip/hip_runtime.h>
#include <hip/hip_fp16.h>
#include <math.h>

#define N_ 100000
#define E_ 3200000
#define K_ 1024
#define D_ 11
#define NBUCK_ 391            // ceil(N/256) buckets of 256 nodes (by src>>8)
#define NPAD_ (NBUCK_ * 256)  // 100096 padded node count
#define CAPB_ 16384           // global slots per bucket (mean fill ~8184)
#define CAP_ 32               // LDS staging slots per bucket (two 64B lines)
#define CAPW_ 33              // padded stride: bank = (b+pos)%32, uniform
#define GB_ 512               // binning blocks (R16's 1024 was slower: DS-pipe bound)
#define CHUNK_ 6256           // edges per binning block (mult of 8; 512*6256 >= E)
#define SA_ 8                 // segments per bucket for k_agg (seg <= 2048)
#define SD_ 8                 // segments per bucket for k_deg
#define XC_ 32                // xmean partial copies (spread atomic contention)
#define RSEG_ 4096            // ready-edge region size (32 regions, mean fill ~1k)
#define RSTRIDE_ 16           // region counters padded to one 64B line each

static inline size_t align512(size_t x) { return (x + 511) & ~(size_t)511; }

__device__ inline float2 h2f(unsigned int u) {
    __half2 h = *reinterpret_cast<__half2*>(&u);
    return __half22float2(h);
}

// ------- prep: zero state, seed cursors, pad x->fp16, flag via binsearch ----
__global__ void k_prep(const float* __restrict__ x, const int* __restrict__ ready,
                       __half* __restrict__ xh,
                       int* __restrict__ deg, float* __restrict__ pr_raw,
                       unsigned char* __restrict__ flag, float* __restrict__ xpart,
                       int* __restrict__ bcur, int* __restrict__ rcntp) {
    int i = blockIdx.x * blockDim.x + threadIdx.x;
    if (i < N_ * 16) {
        int n = i >> 4, j = i & 15;
        if (j < D_) xh[i] = __float2half_rn(x[n * D_ + j]);
        // j==11: dis (k_dis); 12..15: never read
    }
    if (i < N_) {
        deg[i] = 0; pr_raw[i] = 0.f;
        // membership of i in sorted ready[] (binary search, dups ok)
        int lo = 0, hi = K_ - 1, f = 0;
        while (lo <= hi) {
            int mid = (lo + hi) >> 1;
            int v = ready[mid];
            if (v == i) { f = 1; break; }
            if (v < i) lo = mid + 1; else hi = mid - 1;
        }
        flag[i] = (unsigned char)f;
    }
    if (i < XC_ * 64) xpart[i] = 0.f;
    if (i < NBUCK_) bcur[i] = i * CAPB_;
    if (i < 32 * RSTRIDE_) rcntp[i] = 0;
}

// ---- bucket partition (R15 form): stage whole chunk, single drain ----------
// pack = (src&255)<<17 | dst
__global__ __launch_bounds__(256) void k_bin(const int* __restrict__ src,
                                             const int* __restrict__ dst,
                                             int* __restrict__ bcur,
                                             int* __restrict__ gbuf) {
    __shared__ int sbuf[NBUCK_ * CAPW_];   // ~51.6 KB, stride 33
    __shared__ int scnt[NBUCK_];
    int t = threadIdx.x;
    for (int b = t; b < NBUCK_; b += 256) scnt[b] = 0;
    __syncthreads();
    long e0 = (long)blockIdx.x * CHUNK_;
    for (int r = 0; r < CHUNK_; r += 2048) {
        int off = r + t * 8;
        long i0 = e0 + off;
        if (off < CHUNK_ && i0 + 7 < E_) {   // CHUNK_%8==0: all-or-nothing
            int4 s0 = *(const int4*)(src + i0);
            int4 s1 = *(const int4*)(src + i0 + 4);
            int4 d0 = *(const int4*)(dst + i0);
            int4 d1 = *(const int4*)(dst + i0 + 4);
            int ss[8] = {s0.x, s0.y, s0.z, s0.w, s1.x, s1.y, s1.z, s1.w};
            int dd[8] = {d0.x, d0.y, d0.z, d0.w, d1.x, d1.y, d1.z, d1.w};
#pragma unroll
            for (int q = 0; q < 8; q++) {
                int b = ss[q] >> 8;
                int pack = ((ss[q] & 255) << 17) | dd[q];
                int pos = atomicAdd(&scnt[b], 1);
                if (pos < CAP_) sbuf[b * CAPW_ + pos] = pack;
                else gbuf[atomicAdd(&bcur[b], 1)] = pack;  // ~few edges/launch
            }
        }
    }
    __syncthreads();
    // single drain: up to two 64B-line flushes + contiguous partial per bucket
    for (int b = t; b < NBUCK_; b += 256) {
        int c = min(scnt[b], CAP_);
        while (c >= 16) {
            int g = atomicAdd(&bcur[b], 16);
            c -= 16;
            if ((g & 3) == 0) {
                int4* gp = (int4*)(gbuf + g);
#pragma unroll
                for (int q = 0; q < 4; q++)
                    gp[q] = make_int4(sbuf[b*CAPW_ + c + 4*q],
                                      sbuf[b*CAPW_ + c + 4*q + 1],
                                      sbuf[b*CAPW_ + c + 4*q + 2],
                                      sbuf[b*CAPW_ + c + 4*q + 3]);
            } else {
                for (int k = 0; k < 16; k++) gbuf[g + k] = sbuf[b*CAPW_ + c + k];
            }
        }
        if (c > 0) {
            int g = atomicAdd(&bcur[b], c);
            for (int k = 0; k < c; k++) gbuf[g + k] = sbuf[b*CAPW_ + k];
        }
    }
}

// ---------------- per-bucket-segment degree hist (int4 loads) ---------------
__global__ __launch_bounds__(256) void k_deg(const int* __restrict__ bcur,
                                             const int* __restrict__ gbuf,
                                             int* __restrict__ deg) {
    __shared__ int hist[256];
    int t = threadIdx.x, b = blockIdx.x, s = blockIdx.y;
    hist[t] = 0;
    __syncthreads();
    int base = b * CAPB_;
    int cnt = min(bcur[b] - base, CAPB_);
    int seg = (((cnt + SD_ - 1) / SD_) + 3) & ~3;   // mult of 4: int4-aligned lo
    int lo = s * seg, hi = min(lo + seg, cnt);
    int p = lo + t * 4;
    for (; p + 3 < hi; p += 1024) {
        int4 v = *(const int4*)(gbuf + base + p);
        atomicAdd(&hist[v.x >> 17], 1);
        atomicAdd(&hist[v.y >> 17], 1);
        atomicAdd(&hist[v.z >> 17], 1);
        atomicAdd(&hist[v.w >> 17], 1);
    }
    if (p < hi) {   // tail group (<4)
        for (int q = p; q < hi; q++) atomicAdd(&hist[gbuf[base + q] >> 17], 1);
    }
    __syncthreads();
    int node = (b << 8) + t;
    if (node < N_ && hist[t]) atomicAdd(&deg[node], hist[t]);
}

// ---------------- dis = rsqrt(deg+1); pack fp16 copy into xh slot 11 --------
__global__ void k_dis(const int* __restrict__ deg, float* __restrict__ dis,
                      __half* __restrict__ xh) {
    int i = blockIdx.x * blockDim.x + threadIdx.x;
    if (i >= N_) return;
    float dv = rsqrtf((float)(deg[i] + 1));
    dis[i] = dv;
    xh[(size_t)i * 16 + 11] = __float2half_rn(dv);
}

// ------- k_agg: LDS counting-sort by node, register accumulate --------------
// + ready-edge extraction with PADDED region counters (R14 retry: the +10us
// there is hypothesized to be same-line rcnt atomics; rcntp is 64B-strided)
__global__ __launch_bounds__(256) void k_agg(const int* __restrict__ bcur,
                                             const int* __restrict__ gbuf,
                                             const __half* __restrict__ xh,
                                             const unsigned char* __restrict__ flag,
                                             float* __restrict__ upart,
                                             int* __restrict__ rcntp,
                                             int2* __restrict__ redge) {
    __shared__ int sorted[2048];   // seg <= ceil(16384/8) = 2048
    __shared__ int hist[256];
    __shared__ int incl[256];
    __shared__ int offa[256];
    int t = threadIdx.x, b = blockIdx.x, s = blockIdx.y;
    hist[t] = 0;
    __syncthreads();
    int base = b * CAPB_;
    int cnt = min(bcur[b] - base, CAPB_);
    int seg = (cnt + SA_ - 1) / SA_;
    int lo = s * seg, hi = min(lo + seg, cnt);
    int segn = hi - lo;                       // <= 2048
    int kmax = (segn + 255) >> 8;             // <= 8
    int pk[8], rk[8];
    for (int k = 0; k < kmax; k++) {
        int idx = lo + (k << 8) + t;
        if (idx < hi) {
            pk[k] = gbuf[base + idx];         // coalesced
            rk[k] = atomicAdd(&hist[pk[k] >> 17], 1);
        } else pk[k] = -1;
    }
    __syncthreads();
    incl[t] = hist[t];
    __syncthreads();
    for (int off = 1; off < 256; off <<= 1) {
        int v = (t >= off) ? incl[t - off] : 0;
        __syncthreads();
        incl[t] += v;
        __syncthreads();
    }
    offa[t] = incl[t] - hist[t];
    __syncthreads();
    for (int k = 0; k < kmax; k++) {
        if (pk[k] >= 0) sorted[offa[pk[k] >> 17] + rk[k]] = pk[k];
    }
    __syncthreads();
    int my_start = offa[t], my_cnt = hist[t];
    int node = (b << 8) + t;
    const uint4* xr = (const uint4*)xh;
    float acc[D_];
#pragma unroll
    for (int j = 0; j < D_; j++) acc[j] = 0.f;
    int i = 0;
    for (; i + 3 < my_cnt; i += 4) {          // 4-edge ILP batch
        int pp[4];
#pragma unroll
        for (int q = 0; q < 4; q++) pp[q] = sorted[my_start + i + q];
        uint4 A[4], B[4];
#pragma unroll
        for (int q = 0; q < 4; q++) {
            size_t r = (size_t)(pp[q] & 131071) * 2;
            A[q] = xr[r]; B[q] = xr[r + 1];
        }
#pragma unroll
        for (int q = 0; q < 4; q++) {
            float2 f0 = h2f(A[q].x), f1 = h2f(A[q].y), f2 = h2f(A[q].z);
            float2 f3 = h2f(A[q].w), f4 = h2f(B[q].x), f5 = h2f(B[q].y);
            float w = f5.y;   // dis[d]
            acc[0]  = fmaf(w, f0.x, acc[0]);
            acc[1]  = fmaf(w, f0.y, acc[1]);
            acc[2]  = fmaf(w, f1.x, acc[2]);
            acc[3]  = fmaf(w, f1.y, acc[3]);
            acc[4]  = fmaf(w, f2.x, acc[4]);
            acc[5]  = fmaf(w, f2.y, acc[5]);
            acc[6]  = fmaf(w, f3.x, acc[6]);
            acc[7]  = fmaf(w, f3.y, acc[7]);
            acc[8]  = fmaf(w, f4.x, acc[8]);
            acc[9]  = fmaf(w, f4.y, acc[9]);
            acc[10] = fmaf(w, f5.x, acc[10]);
        }
    }
    for (; i < my_cnt; i++) {
        int pack = sorted[my_start + i];
        size_t r = (size_t)(pack & 131071) * 2;
        uint4 A = xr[r], B = xr[r + 1];
        float2 f0 = h2f(A.x), f1 = h2f(A.y), f2 = h2f(A.z);
        float2 f3 = h2f(A.w), f4 = h2f(B.x), f5 = h2f(B.y);
        float w = f5.y;
        acc[0]  = fmaf(w, f0.x, acc[0]);
        acc[1]  = fmaf(w, f0.y, acc[1]);
        acc[2]  = fmaf(w, f1.x, acc[2]);
        acc[3]  = fmaf(w, f1.y, acc[3]);
        acc[4]  = fmaf(w, f2.x, acc[4]);
        acc[5]  = fmaf(w, f2.y, acc[5]);
        acc[6]  = fmaf(w, f3.x, acc[6]);
        acc[7]  = fmaf(w, f3.y, acc[7]);
        acc[8]  = fmaf(w, f4.x, acc[8]);
        acc[9]  = fmaf(w, f4.y, acc[9]);
        acc[10] = fmaf(w, f5.x, acc[10]);
    }
    float* dst = upart + ((size_t)s * NPAD_ + node) * 12;
    ((float4*)dst)[0] = make_float4(acc[0], acc[1], acc[2],  acc[3]);
    ((float4*)dst)[1] = make_float4(acc[4], acc[5], acc[6],  acc[7]);
    ((float4*)dst)[2] = make_float4(acc[8], acc[9], acc[10], 0.f);

    // ready-edge extraction (~1% of threads): padded counters, no barriers
    if (node < N_ && my_cnt > 0 && flag[node]) {
        int r = (b * SA_ + s) & 31;
        int slot = atomicAdd(&rcntp[r * RSTRIDE_], my_cnt);
        int lim = min(my_cnt, max(0, RSEG_ - slot));
        for (int i2 = 0; i2 < lim; i2++)
            redge[(r << 12) + slot + i2] =
                make_int2(node, sorted[my_start + i2] & 131071);
    }
}

// ---------------- slice reduction: u12[slot] = sum_s upart[s][slot] ---------
__global__ __launch_bounds__(256) void k_red(const float* __restrict__ upart,
                                             float* __restrict__ u12) {
    int slot = blockIdx.x * blockDim.x + threadIdx.x;
    const int TOT = NPAD_ * 3;
    if (slot >= TOT) return;
    const float4* up = (const float4*)upart;
    float4 a = up[slot];
#pragma unroll
    for (int s = 1; s < SA_; s++) {
        float4 v = up[(size_t)s * TOT + slot];
        a.x += v.x; a.y += v.y; a.z += v.z; a.w += v.w;
    }
    ((float4*)u12)[slot] = a;
}

// ------- per-node transform: 4 threads/node, register h, shfl reductions ----
__global__ __launch_bounds__(256) void k_node(
    const float* __restrict__ u12, const float* __restrict__ x,
    const float* __restrict__ dis,
    const float* __restrict__ W1, const float* __restrict__ b1,
    const float* __restrict__ W2,
    float* __restrict__ hd, float* __restrict__ xpart) {
    __shared__ float sW1[D_ * 64];
    __shared__ float sb1[64];
    __shared__ float sW2[75];
    __shared__ float smean[64];
    int t = threadIdx.x;
    for (int k = t; k < D_ * 64; k += 256) sW1[k] = W1[k];
    if (t < 64) { sb1[t] = b1[t]; smean[t] = 0.f; }
    if (t < 75) sW2[t] = W2[t];
    __syncthreads();

    int nl = t >> 2, q = t & 3;
    int node = blockIdx.x * 64 + nl;
    bool valid = node < N_;
    float hreg[16];
    float h2v = 0.f;
    float di = 0.f;
    if (valid) {
        const float4* up = (const float4*)(u12 + (size_t)node * 12);
        float4 u0 = up[0], u1 = up[1], u2 = up[2];
        float acc[D_] = {u0.x, u0.y, u0.z, u0.w, u1.x, u1.y, u1.z, u1.w,
                         u2.x, u2.y, u2.z};
        di = dis[node];
        float xr_[D_], g[D_];
#pragma unroll
        for (int j = 0; j < D_; j++) xr_[j] = x[(size_t)node * D_ + j];
#pragma unroll
        for (int j = 0; j < D_; j++) g[j] = di * (acc[j] + di * xr_[j]);

        int fbase = q << 4;
#pragma unroll
        for (int j = 0; j < 16; j++) {
            int f = fbase + j;
            float a = sb1[f];
#pragma unroll
            for (int jj = 0; jj < D_; jj++) a = fmaf(g[jj], sW1[jj * 64 + f], a);
            float hf = fmaxf(a, 0.f);
            hreg[j] = hf;
            h2v = fmaf(hf, sW2[f], h2v);
        }
        if (q == 0) {
#pragma unroll
            for (int jj = 0; jj < D_; jj++) h2v = fmaf(xr_[jj], sW2[64 + jj], h2v);
        }
    } else {
#pragma unroll
        for (int j = 0; j < 16; j++) hreg[j] = 0.f;
    }
    // h2 = sum of 4 quarter-partials (adjacent lanes)
    h2v += __shfl_xor(h2v, 1);
    h2v += __shfl_xor(h2v, 2);
    if (valid && q == 0) hd[node] = di * h2v;  // pre-scaled for conv2

    // smean: reduce each feature across the 16 same-quarter lanes (stride 4)
    int lane = t & 63;
#pragma unroll
    for (int j = 0; j < 16; j++) {
        float v = hreg[j];
        v += __shfl_xor(v, 4);
        v += __shfl_xor(v, 8);
        v += __shfl_xor(v, 16);
        v += __shfl_xor(v, 32);
        if (lane < 4) atomicAdd(&smean[(lane << 4) + j], v);
    }
    __syncthreads();
    // spread copies: block b -> copy b&(XC_-1); ~49 blocks/copy, no hot line
    if (t < 64) atomicAdd(&xpart[((blockIdx.x & (XC_ - 1)) << 6) + t], smean[t]);
}

// ---------------- conv2: process the compact ready-edge list ----------------
__global__ void k_pr(const int* __restrict__ rcntp, const int2* __restrict__ redge,
                     const float* __restrict__ hd, float* __restrict__ pr_raw) {
    int idx = blockIdx.x * blockDim.x + threadIdx.x;
    int r = idx >> 12;            // region
    int off = idx & (RSEG_ - 1);
    if (r < 32 && off < min(rcntp[r * RSTRIDE_], RSEG_)) {
        int2 e = redge[(r << 12) + off];
        atomicAdd(&pr_raw[e.x], hd[e.y]);
    }
}

// ---------------- finalize: logits, prob_nothing, v, softmax ----------------
__global__ __launch_bounds__(1024) void k_final(
    const int* __restrict__ ready, const float* __restrict__ dis,
    const float* __restrict__ hd, const float* __restrict__ pr_raw,
    const float* __restrict__ xpart,
    const float* __restrict__ b2,
    const float* __restrict__ Wd, const float* __restrict__ bd,
    const float* __restrict__ Wv, const float* __restrict__ bv,
    float* __restrict__ out) {
    __shared__ float xm[64];
    __shared__ float red[1024];
    __shared__ float s_max, s_sum, s_pn, s_v;
    int t = threadIdx.x;
    if (t < 64) {
        float s = 0.f;
#pragma unroll
        for (int c = 0; c < XC_; c++) s += xpart[(c << 6) + t];
        xm[t] = s * (1.0f / N_);
    }
    __syncthreads();
    if (t == 0) {
        float pn = bd[0], vv = bv[0];
        for (int f = 0; f < 64; f++) { pn += xm[f] * Wd[f]; vv += xm[f] * Wv[f]; }
        s_pn = pn; s_v = vv;
    }
    int r = ready[t];
    float dr = dis[r];
    float l = dr * (pr_raw[r] + hd[r]) + b2[0];   // dr*Σhd[d] + dr²h2[r] + b2
    __syncthreads();
    float pn = s_pn;
    red[t] = (t == 0) ? fmaxf(l, pn) : l;
    __syncthreads();
    for (int sft = 512; sft > 0; sft >>= 1) {
        if (t < sft) red[t] = fmaxf(red[t], red[t + sft]);
        __syncthreads();
    }
    if (t == 0) s_max = red[0];
    __syncthreads();
    float m = s_max;
    float el = expf(l - m);
    red[t] = el + ((t == 0) ? expf(pn - m) : 0.f);
    __syncthreads();
    for (int sft = 512; sft > 0; sft >>= 1) {
        if (t < sft) red[t] += red[t + sft];
        __syncthreads();
    }
    if (t == 0) s_sum = red[0];
    __syncthreads();
    float inv = 1.0f / s_sum;
    out[t] = el * inv;
    if (t == 0) {
        out[K_] = expf(pn - m) * inv;   // prob_nothing slot
        out[K_ + 1] = s_v;              // v
    }
}

extern "C" void kernel_launch(void* const* d_in, const int* in_sizes, int n_in,
                              void* d_out, int out_size, void* d_ws, size_t ws_size,
                              hipStream_t stream) {
    const float* x    = (const float*)d_in[0];
    const int*   ei   = (const int*)d_in[1];
    const int*   src  = ei;
    const int*   dst  = ei + E_;
    const int*   ready= (const int*)d_in[2];
    const float* W1   = (const float*)d_in[3];
    const float* b1   = (const float*)d_in[4];
    const float* W2   = (const float*)d_in[5];
    const float* b2   = (const float*)d_in[6];
    const float* Wd   = (const float*)d_in[7];
    const float* bd   = (const float*)d_in[8];
    const float* Wv   = (const float*)d_in[9];
    const float* bv   = (const float*)d_in[10];
    float* out = (float*)d_out;

    char* ws = (char*)d_ws;
    size_t o = 0;
    int*   bcur   = (int*)(ws + o);          o += align512(NBUCK_ * sizeof(int));
    int*   rcntp  = (int*)(ws + o);          o += align512(32 * RSTRIDE_ * sizeof(int));
    int*   gbuf   = (int*)(ws + o);          o += align512((size_t)NBUCK_ * CAPB_ * sizeof(int));
    float* upart  = (float*)(ws + o);        o += align512((size_t)SA_ * NPAD_ * 12 * sizeof(float));
    float* u12    = (float*)(ws + o);        o += align512((size_t)NPAD_ * 12 * sizeof(float));
    __half* xh    = (__half*)(ws + o);       o += align512((size_t)N_ * 16 * sizeof(__half));
    int2*  redge  = (int2*)(ws + o);         o += align512((size_t)32 * RSEG_ * sizeof(int2));
    int*   deg    = (int*)(ws + o);          o += align512(N_ * sizeof(int));
    float* dis    = (float*)(ws + o);        o += align512(N_ * sizeof(float));
    float* hd     = (float*)(ws + o);        o += align512(N_ * sizeof(float));
    float* pr_raw = (float*)(ws + o);        o += align512(N_ * sizeof(float));
    unsigned char* flag = (unsigned char*)(ws + o); o += align512(N_);
    float* xpart  = (float*)(ws + o);        o += align512(XC_ * 64 * sizeof(float));

    const int B = 256;
    int g_node  = (N_ + B - 1) / B;
    int g_node4 = (N_ + 63) / 64;          // 4 threads per node
    int g_prep  = (N_ * 16 + B - 1) / B;
    int g_red   = (NPAD_ * 3 + B - 1) / B;
    int g_pr    = (32 * RSEG_) / B;
    dim3 gdeg(NBUCK_, SD_);
    dim3 gagg(NBUCK_, SA_);

    k_prep <<<g_prep, B, 0, stream>>>(x, ready, xh, deg, pr_raw, flag, xpart, bcur, rcntp);
    k_bin  <<<GB_, B, 0, stream>>>(src, dst, bcur, gbuf);
    k_deg  <<<gdeg, B, 0, stream>>>(bcur, gbuf, deg);
    k_dis  <<<g_node, B, 0, stream>>>(deg, dis, xh);
    k_agg  <<<gagg, B, 0, stream>>>(bcur, gbuf, xh, flag, upart, rcntp, redge);
    k_red  <<<g_red, B, 0, stream>>>(upart, u12);
    k_node <<<g_node4, B, 0, stream>>>(u12, x, dis, W1, b1, W2, hd, xpart);
    k_pr   <<<g_pr, B, 0, stream>>>(rcntp, redge, hd, pr_raw);
    k_final<<<1, 1024, 0, stream>>>(ready, dis, hd, pr_raw, xpart,
                                    b2, Wd, bd, Wv, bv, out);
}

// Round 18
// 206.449 us; speedup vs baseline: 1.0353x; 1.0225x over previous
//
#include <hip/hip_runtime.h>
#include <hip/hip_fp16.h>
#include <math.h>

#define N_ 100000
#define E_ 3200000
#define K_ 1024
#define D_ 11
#define NBUCK_ 391            // ceil(N/256) buckets of 256 nodes (by src>>8)
#define NPAD_ (NBUCK_ * 256)  // 100096 padded node count
#define CAPB_ 16384           // global slots per bucket (mean fill ~8184)
#define CAP_ 32               // LDS staging slots per bucket (two 64B lines)
#define CAPW_ 33              // padded stride: bank = (b+pos)%32, uniform
#define GB_ 512               // binning blocks (1024 was slower: DS-pipe bound)
#define CHUNK_ 6256           // edges per binning block (mult of 8; 512*6256 >= E)
#define SA_ 8                 // segments per bucket for k_agg (seg <= 2048)
#define SD_ 4                 // segments per bucket for k_deg (R18: was 8)
#define XC_ 32                // xmean partial copies (spread atomic contention)
#define RSEG_ 4096            // ready-edge region size (32 regions, mean fill ~1k)
#define RSTRIDE_ 16           // region counters padded to one 64B line each

static inline size_t align512(size_t x) { return (x + 511) & ~(size_t)511; }

__device__ inline float2 h2f(unsigned int u) {
    __half2 h = *reinterpret_cast<__half2*>(&u);
    return __half22float2(h);
}

// ------- prep: zero state, seed cursors, pad x->fp16, flag via binsearch ----
__global__ void k_prep(const float* __restrict__ x, const int* __restrict__ ready,
                       __half* __restrict__ xh,
                       int* __restrict__ deg, float* __restrict__ pr_raw,
                       unsigned char* __restrict__ flag, float* __restrict__ xpart,
                       int* __restrict__ bcur, int* __restrict__ rcntp) {
    int i = blockIdx.x * blockDim.x + threadIdx.x;
    if (i < N_ * 16) {
        int n = i >> 4, j = i & 15;
        if (j < D_) xh[i] = __float2half_rn(x[n * D_ + j]);
        // j==11: dis (k_dis); 12..15: never read
    }
    if (i < N_) {
        deg[i] = 0; pr_raw[i] = 0.f;
        // membership of i in sorted ready[] (binary search, dups ok)
        int lo = 0, hi = K_ - 1, f = 0;
        while (lo <= hi) {
            int mid = (lo + hi) >> 1;
            int v = ready[mid];
            if (v == i) { f = 1; break; }
            if (v < i) lo = mid + 1; else hi = mid - 1;
        }
        flag[i] = (unsigned char)f;
    }
    if (i < XC_ * 64) xpart[i] = 0.f;
    if (i < NBUCK_) bcur[i] = i * CAPB_;
    if (i < 32 * RSTRIDE_) rcntp[i] = 0;
}

// ---- bucket partition: stage whole chunk (CAP bounds it), single drain -----
// pack = (src&255)<<17 | dst
__global__ __launch_bounds__(256) void k_bin(const int* __restrict__ src,
                                             const int* __restrict__ dst,
                                             int* __restrict__ bcur,
                                             int* __restrict__ gbuf) {
    __shared__ int sbuf[NBUCK_ * CAPW_];   // ~51.6 KB, stride 33
    __shared__ int scnt[NBUCK_];
    int t = threadIdx.x;
    for (int b = t; b < NBUCK_; b += 256) scnt[b] = 0;
    __syncthreads();
    long e0 = (long)blockIdx.x * CHUNK_;
    for (int r = 0; r < CHUNK_; r += 2048) {
        int off = r + t * 8;
        long i0 = e0 + off;
        if (off < CHUNK_ && i0 + 7 < E_) {   // CHUNK_%8==0: all-or-nothing
            int4 s0 = *(const int4*)(src + i0);
            int4 s1 = *(const int4*)(src + i0 + 4);
            int4 d0 = *(const int4*)(dst + i0);
            int4 d1 = *(const int4*)(dst + i0 + 4);
            int ss[8] = {s0.x, s0.y, s0.z, s0.w, s1.x, s1.y, s1.z, s1.w};
            int dd[8] = {d0.x, d0.y, d0.z, d0.w, d1.x, d1.y, d1.z, d1.w};
#pragma unroll
            for (int q = 0; q < 8; q++) {
                int b = ss[q] >> 8;
                int pack = ((ss[q] & 255) << 17) | dd[q];
                int pos = atomicAdd(&scnt[b], 1);
                if (pos < CAP_) sbuf[b * CAPW_ + pos] = pack;
                else gbuf[atomicAdd(&bcur[b], 1)] = pack;  // ~few edges/launch
            }
        }
    }
    __syncthreads();
    // single drain: up to two 64B-line flushes + contiguous partial per bucket
    for (int b = t; b < NBUCK_; b += 256) {
        int c = min(scnt[b], CAP_);
        while (c >= 16) {
            int g = atomicAdd(&bcur[b], 16);
            c -= 16;
            if ((g & 3) == 0) {
                int4* gp = (int4*)(gbuf + g);
#pragma unroll
                for (int q = 0; q < 4; q++)
                    gp[q] = make_int4(sbuf[b*CAPW_ + c + 4*q],
                                      sbuf[b*CAPW_ + c + 4*q + 1],
                                      sbuf[b*CAPW_ + c + 4*q + 2],
                                      sbuf[b*CAPW_ + c + 4*q + 3]);
            } else {
                for (int k = 0; k < 16; k++) gbuf[g + k] = sbuf[b*CAPW_ + c + k];
            }
        }
        if (c > 0) {
            int g = atomicAdd(&bcur[b], c);
            for (int k = 0; k < c; k++) gbuf[g + k] = sbuf[b*CAPW_ + k];
        }
    }
}

// ---------------- per-bucket-segment degree hist (int4 loads) ---------------
__global__ __launch_bounds__(256) void k_deg(const int* __restrict__ bcur,
                                             const int* __restrict__ gbuf,
                                             int* __restrict__ deg) {
    __shared__ int hist[256];
    int t = threadIdx.x, b = blockIdx.x, s = blockIdx.y;
    hist[t] = 0;
    __syncthreads();
    int base = b * CAPB_;
    int cnt = min(bcur[b] - base, CAPB_);
    int seg = (((cnt + SD_ - 1) / SD_) + 3) & ~3;   // mult of 4: int4-aligned lo
    int lo = s * seg, hi = min(lo + seg, cnt);
    int p = lo + t * 4;
    for (; p + 3 < hi; p += 1024) {
        int4 v = *(const int4*)(gbuf + base + p);
        atomicAdd(&hist[v.x >> 17], 1);
        atomicAdd(&hist[v.y >> 17], 1);
        atomicAdd(&hist[v.z >> 17], 1);
        atomicAdd(&hist[v.w >> 17], 1);
    }
    if (p < hi) {   // tail group (<4)
        for (int q = p; q < hi; q++) atomicAdd(&hist[gbuf[base + q] >> 17], 1);
    }
    __syncthreads();
    int node = (b << 8) + t;
    if (node < N_ && hist[t]) atomicAdd(&deg[node], hist[t]);
}

// ---------------- dis = rsqrt(deg+1); pack fp16 copy into xh slot 11 --------
__global__ void k_dis(const int* __restrict__ deg, float* __restrict__ dis,
                      __half* __restrict__ xh) {
    int i = blockIdx.x * blockDim.x + threadIdx.x;
    if (i >= N_) return;
    float dv = rsqrtf((float)(deg[i] + 1));
    dis[i] = dv;
    xh[(size_t)i * 16 + 11] = __float2half_rn(dv);
}

// ------- k_agg: LDS counting-sort by node, register accumulate --------------
// + ready-edge extraction with padded region counters
__global__ __launch_bounds__(256) void k_agg(const int* __restrict__ bcur,
                                             const int* __restrict__ gbuf,
                                             const __half* __restrict__ xh,
                                             const unsigned char* __restrict__ flag,
                                             float* __restrict__ upart,
                                             int* __restrict__ rcntp,
                                             int2* __restrict__ redge) {
    __shared__ int sorted[2048];   // seg <= ceil(16384/8) = 2048
    __shared__ int hist[256];
    __shared__ int incl[256];
    __shared__ int offa[256];
    int t = threadIdx.x, b = blockIdx.x, s = blockIdx.y;
    hist[t] = 0;
    __syncthreads();
    int base = b * CAPB_;
    int cnt = min(bcur[b] - base, CAPB_);
    int seg = (cnt + SA_ - 1) / SA_;
    int lo = s * seg, hi = min(lo + seg, cnt);
    int segn = hi - lo;                       // <= 2048
    int kmax = (segn + 255) >> 8;             // <= 8
    int pk[8], rk[8];
    for (int k = 0; k < kmax; k++) {
        int idx = lo + (k << 8) + t;
        if (idx < hi) {
            pk[k] = gbuf[base + idx];         // coalesced
            rk[k] = atomicAdd(&hist[pk[k] >> 17], 1);
        } else pk[k] = -1;
    }
    __syncthreads();
    incl[t] = hist[t];
    __syncthreads();
    for (int off = 1; off < 256; off <<= 1) {
        int v = (t >= off) ? incl[t - off] : 0;
        __syncthreads();
        incl[t] += v;
        __syncthreads();
    }
    offa[t] = incl[t] - hist[t];
    __syncthreads();
    for (int k = 0; k < kmax; k++) {
        if (pk[k] >= 0) sorted[offa[pk[k] >> 17] + rk[k]] = pk[k];
    }
    __syncthreads();
    int my_start = offa[t], my_cnt = hist[t];
    int node = (b << 8) + t;
    const uint4* xr = (const uint4*)xh;
    float acc[D_];
#pragma unroll
    for (int j = 0; j < D_; j++) acc[j] = 0.f;
    int i = 0;
    for (; i + 3 < my_cnt; i += 4) {          // 4-edge ILP batch
        int pp[4];
#pragma unroll
        for (int q = 0; q < 4; q++) pp[q] = sorted[my_start + i + q];
        uint4 A[4], B[4];
#pragma unroll
        for (int q = 0; q < 4; q++) {
            size_t r = (size_t)(pp[q] & 131071) * 2;
            A[q] = xr[r]; B[q] = xr[r + 1];
        }
#pragma unroll
        for (int q = 0; q < 4; q++) {
            float2 f0 = h2f(A[q].x), f1 = h2f(A[q].y), f2 = h2f(A[q].z);
            float2 f3 = h2f(A[q].w), f4 = h2f(B[q].x), f5 = h2f(B[q].y);
            float w = f5.y;   // dis[d]
            acc[0]  = fmaf(w, f0.x, acc[0]);
            acc[1]  = fmaf(w, f0.y, acc[1]);
            acc[2]  = fmaf(w, f1.x, acc[2]);
            acc[3]  = fmaf(w, f1.y, acc[3]);
            acc[4]  = fmaf(w, f2.x, acc[4]);
            acc[5]  = fmaf(w, f2.y, acc[5]);
            acc[6]  = fmaf(w, f3.x, acc[6]);
            acc[7]  = fmaf(w, f3.y, acc[7]);
            acc[8]  = fmaf(w, f4.x, acc[8]);
            acc[9]  = fmaf(w, f4.y, acc[9]);
            acc[10] = fmaf(w, f5.x, acc[10]);
        }
    }
    for (; i < my_cnt; i++) {
        int pack = sorted[my_start + i];
        size_t r = (size_t)(pack & 131071) * 2;
        uint4 A = xr[r], B = xr[r + 1];
        float2 f0 = h2f(A.x), f1 = h2f(A.y), f2 = h2f(A.z);
        float2 f3 = h2f(A.w), f4 = h2f(B.x), f5 = h2f(B.y);
        float w = f5.y;
        acc[0]  = fmaf(w, f0.x, acc[0]);
        acc[1]  = fmaf(w, f0.y, acc[1]);
        acc[2]  = fmaf(w, f1.x, acc[2]);
        acc[3]  = fmaf(w, f1.y, acc[3]);
        acc[4]  = fmaf(w, f2.x, acc[4]);
        acc[5]  = fmaf(w, f2.y, acc[5]);
        acc[6]  = fmaf(w, f3.x, acc[6]);
        acc[7]  = fmaf(w, f3.y, acc[7]);
        acc[8]  = fmaf(w, f4.x, acc[8]);
        acc[9]  = fmaf(w, f4.y, acc[9]);
        acc[10] = fmaf(w, f5.x, acc[10]);
    }
    float* dst = upart + ((size_t)s * NPAD_ + node) * 12;
    ((float4*)dst)[0] = make_float4(acc[0], acc[1], acc[2],  acc[3]);
    ((float4*)dst)[1] = make_float4(acc[4], acc[5], acc[6],  acc[7]);
    ((float4*)dst)[2] = make_float4(acc[8], acc[9], acc[10], 0.f);

    // ready-edge extraction (~1% of threads): padded counters, no barriers
    if (node < N_ && my_cnt > 0 && flag[node]) {
        int r = (b * SA_ + s) & 31;
        int slot = atomicAdd(&rcntp[r * RSTRIDE_], my_cnt);
        int lim = min(my_cnt, max(0, RSEG_ - slot));
        for (int i2 = 0; i2 < lim; i2++)
            redge[(r << 12) + slot + i2] =
                make_int2(node, sorted[my_start + i2] & 131071);
    }
}

// ------- per-node transform: 4 threads/node, fused slice reduction ----------
// R18: k_red folded in — thread q (<3) sums float4 #q across the 8 upart
// slices; 12 shfls broadcast the 11 sums to the quad. Deletes the u12 buffer.
__global__ __launch_bounds__(256) void k_node(
    const float* __restrict__ upart, const float* __restrict__ x,
    const float* __restrict__ dis,
    const float* __restrict__ W1, const float* __restrict__ b1,
    const float* __restrict__ W2,
    float* __restrict__ hd, float* __restrict__ xpart) {
    __shared__ float sW1[D_ * 64];
    __shared__ float sb1[64];
    __shared__ float sW2[75];
    __shared__ float smean[64];
    int t = threadIdx.x;
    for (int k = t; k < D_ * 64; k += 256) sW1[k] = W1[k];
    if (t < 64) { sb1[t] = b1[t]; smean[t] = 0.f; }
    if (t < 75) sW2[t] = W2[t];
    __syncthreads();

    int nl = t >> 2, q = t & 3;
    int node = blockIdx.x * 64 + nl;
    bool valid = node < N_;

    // cooperative slice reduction (replaces k_red)
    float4 mine = make_float4(0.f, 0.f, 0.f, 0.f);
    if (valid && q < 3) {
        const int TOT3 = NPAD_ * 3;               // float4 slots per slice
        int slot = node * 3 + q;
        const float4* up = (const float4*)upart;
        float4 a = up[slot];
#pragma unroll
        for (int s = 1; s < SA_; s++) {
            float4 v = up[(size_t)s * TOT3 + slot];
            a.x += v.x; a.y += v.y; a.z += v.z; a.w += v.w;
        }
        mine = a;
    }
    int lb = (t & 63) & ~3;   // quad-base lane within the wave
    float acc[D_];
    acc[0]  = __shfl(mine.x, lb);     acc[1]  = __shfl(mine.y, lb);
    acc[2]  = __shfl(mine.z, lb);     acc[3]  = __shfl(mine.w, lb);
    acc[4]  = __shfl(mine.x, lb + 1); acc[5]  = __shfl(mine.y, lb + 1);
    acc[6]  = __shfl(mine.z, lb + 1); acc[7]  = __shfl(mine.w, lb + 1);
    acc[8]  = __shfl(mine.x, lb + 2); acc[9]  = __shfl(mine.y, lb + 2);
    acc[10] = __shfl(mine.z, lb + 2);

    float hreg[16];
    float h2v = 0.f;
    float di = 0.f;
    if (valid) {
        di = dis[node];
        float xr_[D_], g[D_];
#pragma unroll
        for (int j = 0; j < D_; j++) xr_[j] = x[(size_t)node * D_ + j];
#pragma unroll
        for (int j = 0; j < D_; j++) g[j] = di * (acc[j] + di * xr_[j]);

        int fbase = q << 4;
#pragma unroll
        for (int j = 0; j < 16; j++) {
            int f = fbase + j;
            float a = sb1[f];
#pragma unroll
            for (int jj = 0; jj < D_; jj++) a = fmaf(g[jj], sW1[jj * 64 + f], a);
            float hf = fmaxf(a, 0.f);
            hreg[j] = hf;
            h2v = fmaf(hf, sW2[f], h2v);
        }
        if (q == 0) {
#pragma unroll
            for (int jj = 0; jj < D_; jj++) h2v = fmaf(xr_[jj], sW2[64 + jj], h2v);
        }
    } else {
#pragma unroll
        for (int j = 0; j < 16; j++) hreg[j] = 0.f;
    }
    // h2 = sum of 4 quarter-partials (adjacent lanes)
    h2v += __shfl_xor(h2v, 1);
    h2v += __shfl_xor(h2v, 2);
    if (valid && q == 0) hd[node] = di * h2v;  // pre-scaled for conv2

    // smean: reduce each feature across the 16 same-quarter lanes (stride 4)
    int lane = t & 63;
#pragma unroll
    for (int j = 0; j < 16; j++) {
        float v = hreg[j];
        v += __shfl_xor(v, 4);
        v += __shfl_xor(v, 8);
        v += __shfl_xor(v, 16);
        v += __shfl_xor(v, 32);
        if (lane < 4) atomicAdd(&smean[(lane << 4) + j], v);
    }
    __syncthreads();
    // spread copies: block b -> copy b&(XC_-1); ~49 blocks/copy, no hot line
    if (t < 64) atomicAdd(&xpart[((blockIdx.x & (XC_ - 1)) << 6) + t], smean[t]);
}

// ---------------- conv2: process the compact ready-edge list ----------------
__global__ void k_pr(const int* __restrict__ rcntp, const int2* __restrict__ redge,
                     const float* __restrict__ hd, float* __restrict__ pr_raw) {
    int idx = blockIdx.x * blockDim.x + threadIdx.x;
    int r = idx >> 12;            // region
    int off = idx & (RSEG_ - 1);
    if (r < 32 && off < min(rcntp[r * RSTRIDE_], RSEG_)) {
        int2 e = redge[(r << 12) + off];
        atomicAdd(&pr_raw[e.x], hd[e.y]);
    }
}

// ---------------- finalize: logits, prob_nothing, v, softmax ----------------
__global__ __launch_bounds__(1024) void k_final(
    const int* __restrict__ ready, const float* __restrict__ dis,
    const float* __restrict__ hd, const float* __restrict__ pr_raw,
    const float* __restrict__ xpart,
    const float* __restrict__ b2,
    const float* __restrict__ Wd, const float* __restrict__ bd,
    const float* __restrict__ Wv, const float* __restrict__ bv,
    float* __restrict__ out) {
    __shared__ float xm[64];
    __shared__ float red[1024];
    __shared__ float s_max, s_sum, s_pn, s_v;
    int t = threadIdx.x;
    if (t < 64) {
        float s = 0.f;
#pragma unroll
        for (int c = 0; c < XC_; c++) s += xpart[(c << 6) + t];
        xm[t] = s * (1.0f / N_);
    }
    __syncthreads();
    if (t == 0) {
        float pn = bd[0], vv = bv[0];
        for (int f = 0; f < 64; f++) { pn += xm[f] * Wd[f]; vv += xm[f] * Wv[f]; }
        s_pn = pn; s_v = vv;
    }
    int r = ready[t];
    float dr = dis[r];
    float l = dr * (pr_raw[r] + hd[r]) + b2[0];   // dr*Σhd[d] + dr²h2[r] + b2
    __syncthreads();
    float pn = s_pn;
    red[t] = (t == 0) ? fmaxf(l, pn) : l;
    __syncthreads();
    for (int sft = 512; sft > 0; sft >>= 1) {
        if (t < sft) red[t] = fmaxf(red[t], red[t + sft]);
        __syncthreads();
    }
    if (t == 0) s_max = red[0];
    __syncthreads();
    float m = s_max;
    float el = expf(l - m);
    red[t] = el + ((t == 0) ? expf(pn - m) : 0.f);
    __syncthreads();
    for (int sft = 512; sft > 0; sft >>= 1) {
        if (t < sft) red[t] += red[t + sft];
        __syncthreads();
    }
    if (t == 0) s_sum = red[0];
    __syncthreads();
    float inv = 1.0f / s_sum;
    out[t] = el * inv;
    if (t == 0) {
        out[K_] = expf(pn - m) * inv;   // prob_nothing slot
        out[K_ + 1] = s_v;              // v
    }
}

extern "C" void kernel_launch(void* const* d_in, const int* in_sizes, int n_in,
                              void* d_out, int out_size, void* d_ws, size_t ws_size,
                              hipStream_t stream) {
    const float* x    = (const float*)d_in[0];
    const int*   ei   = (const int*)d_in[1];
    const int*   src  = ei;
    const int*   dst  = ei + E_;
    const int*   ready= (const int*)d_in[2];
    const float* W1   = (const float*)d_in[3];
    const float* b1   = (const float*)d_in[4];
    const float* W2   = (const float*)d_in[5];
    const float* b2   = (const float*)d_in[6];
    const float* Wd   = (const float*)d_in[7];
    const float* bd   = (const float*)d_in[8];
    const float* Wv   = (const float*)d_in[9];
    const float* bv   = (const float*)d_in[10];
    float* out = (float*)d_out;

    char* ws = (char*)d_ws;
    size_t o = 0;
    int*   bcur   = (int*)(ws + o);          o += align512(NBUCK_ * sizeof(int));
    int*   rcntp  = (int*)(ws + o);          o += align512(32 * RSTRIDE_ * sizeof(int));
    int*   gbuf   = (int*)(ws + o);          o += align512((size_t)NBUCK_ * CAPB_ * sizeof(int));
    float* upart  = (float*)(ws + o);        o += align512((size_t)SA_ * NPAD_ * 12 * sizeof(float));
    __half* xh    = (__half*)(ws + o);       o += align512((size_t)N_ * 16 * sizeof(__half));
    int2*  redge  = (int2*)(ws + o);         o += align512((size_t)32 * RSEG_ * sizeof(int2));
    int*   deg    = (int*)(ws + o);          o += align512(N_ * sizeof(int));
    float* dis    = (float*)(ws + o);        o += align512(N_ * sizeof(float));
    float* hd     = (float*)(ws + o);        o += align512(N_ * sizeof(float));
    float* pr_raw = (float*)(ws + o);        o += align512(N_ * sizeof(float));
    unsigned char* flag = (unsigned char*)(ws + o); o += align512(N_);
    float* xpart  = (float*)(ws + o);        o += align512(XC_ * 64 * sizeof(float));

    const int B = 256;
    int g_node  = (N_ + B - 1) / B;
    int g_node4 = (N_ + 63) / 64;          // 4 threads per node
    int g_prep  = (N_ * 16 + B - 1) / B;
    int g_pr    = (32 * RSEG_) / B;
    dim3 gdeg(NBUCK_, SD_);
    dim3 gagg(NBUCK_, SA_);

    k_prep <<<g_prep, B, 0, stream>>>(x, ready, xh, deg, pr_raw, flag, xpart, bcur, rcntp);
    k_bin  <<<GB_, B, 0, stream>>>(src, dst, bcur, gbuf);
    k_deg  <<<gdeg, B, 0, stream>>>(bcur, gbuf, deg);
    k_dis  <<<g_node, B, 0, stream>>>(deg, dis, xh);
    k_agg  <<<gagg, B, 0, stream>>>(bcur, gbuf, xh, flag, upart, rcntp, redge);
    k_node <<<g_node4, B, 0, stream>>>(upart, x, dis, W1, b1, W2, hd, xpart);
    k_pr   <<<g_pr, B, 0, stream>>>(rcntp, redge, hd, pr_raw);
    k_final<<<1, 1024, 0, stream>>>(ready, dis, hd, pr_raw, xpart,
                                    b2, Wd, bd, Wv, bv, out);
}